// Round 1
// 1342.226 us; speedup vs baseline: 1.6786x; 1.6786x over previous
//
#include <hip/hip_runtime.h>
#include <hip/hip_bf16.h>
#include <cstdint>

#define N_NODES 100000
#define N_EDGES 1600000
#define C_IN    10
#define C_H     128
#define LN_EPS  1e-5f

// ---------------------------------------------------------------------------
// CSR build: histogram of dst (total + poly), exclusive scan, scatter with
// poly edges placed FIRST within each node's segment.
//   row_off[n] .. poly_end[n]   : poly (attr==3) edges
//   poly_end[n] .. row_off[n+1] : remaining edges
// MODE 3 then only walks the poly prefix (5x less gather), and no flag
// masking is needed anywhere.
// ---------------------------------------------------------------------------
__global__ void hist_kernel(const int* __restrict__ dst, const int* __restrict__ attr,
                            int* __restrict__ cnt, int* __restrict__ pcnt) {
    int i = blockIdx.x * blockDim.x + threadIdx.x;
    int stride = gridDim.x * blockDim.x;
    for (; i < N_EDGES; i += stride) {
        int d = dst[i];
        atomicAdd(&cnt[d], 1);
        if (attr[i] == 3) atomicAdd(&pcnt[d], 1);
    }
}

__global__ void scan_kernel(const int* __restrict__ cnt, const int* __restrict__ pcnt,
                            int* __restrict__ row_off, int* __restrict__ poly_end) {
    __shared__ int ps[1024];
    const int t = threadIdx.x;
    const int per = (N_NODES + 1023) / 1024;
    const int beg = t * per;
    const int end = min(beg + per, N_NODES);
    int s = 0;
    for (int i = beg; i < end; ++i) s += cnt[i];
    ps[t] = s;
    __syncthreads();
    for (int off = 1; off < 1024; off <<= 1) {
        int v = (t >= off) ? ps[t - off] : 0;
        __syncthreads();
        ps[t] += v;
        __syncthreads();
    }
    int ex = (t == 0) ? 0 : ps[t - 1];
    for (int i = beg; i < end; ++i) {
        row_off[i]  = ex;
        poly_end[i] = ex + pcnt[i];
        ex += cnt[i];
    }
    if (t == 1023) row_off[N_NODES] = ex;  // == N_EDGES
}

__global__ void scatter_kernel(const int* __restrict__ src, const int* __restrict__ dst,
                               const int* __restrict__ attr,
                               const int* __restrict__ row_off, const int* __restrict__ poly_end,
                               int* __restrict__ curP, int* __restrict__ curR,
                               int* __restrict__ pack) {
    int i = blockIdx.x * blockDim.x + threadIdx.x;
    int stride = gridDim.x * blockDim.x;
    for (; i < N_EDGES; i += stride) {
        int d = dst[i];
        int pos;
        if (attr[i] == 3) pos = row_off[d]  + atomicAdd(&curP[d], 1);
        else              pos = poly_end[d] + atomicAdd(&curR[d], 1);
        pack[pos] = src[i];  // order within a segment is nondeterministic; max is invariant
    }
}

// ---------------------------------------------------------------------------
// Input projection: h0 = relu(x @ W_in^T + b_in).  One wave per node,
// lane l owns channels (l, l+64). W_in in LDS with stride 11 (gcd(11,32)=1).
// ---------------------------------------------------------------------------
__global__ void in_proj_kernel(const float* __restrict__ x, const float* __restrict__ Win,
                               const float* __restrict__ bin, float* __restrict__ h0) {
    __shared__ float Wl[C_H * 11];
    for (int i = threadIdx.x; i < C_H * C_IN; i += blockDim.x) {
        int c = i / C_IN, k = i % C_IN;
        Wl[c * 11 + k] = Win[i];
    }
    __syncthreads();
    const int l = threadIdx.x & 63, wid = threadIdx.x >> 6;
    const int wave = blockIdx.x * 4 + wid, nw = gridDim.x * 4;
    const float b0 = bin[l], b1 = bin[l + 64];
    for (int n = wave; n < N_NODES; n += nw) {
        float xr[C_IN];
#pragma unroll
        for (int k = 0; k < C_IN; ++k) xr[k] = x[n * C_IN + k];  // wave-uniform
        float a0 = b0, a1 = b1;
#pragma unroll
        for (int k = 0; k < C_IN; ++k) {
            a0 = fmaf(xr[k], Wl[l * 11 + k], a0);
            a1 = fmaf(xr[k], Wl[(l + 64) * 11 + k], a1);
        }
        h0[(size_t)n * C_H + l]      = fmaxf(a0, 0.f);
        h0[(size_t)n * C_H + l + 64] = fmaxf(a1, 0.f);
    }
}

// ---------------------------------------------------------------------------
// Fused MPNN layer: gather-max -> GEMM -> LN -> residual ReLU -> epilogue
// MODE 0: hop0  (hout, nf  = o*sg)
// MODE 1: hop1  (hout, nf += o*sg)
// MODE 2: hop2  (no hout, nf += o*sg, v3 = max over rem nodes of nf)
// MODE 3: final (no hout/nf, poly-only agg via poly_end, v2 = max over sinks)
// One wave per node, 4 nodes per wave-iteration (NPW=4).
// Lane l: gathers channels (2l,2l+1); computes output channels (l,l+64).
// Gather is software-pipelined 8 edges deep: 8 independent row loads in
// flight per wave before any fmax consumes them (MLP 1 -> 8).
// ---------------------------------------------------------------------------
#define NPW 4

template <int MODE>
__global__ __launch_bounds__(256) void layer_kernel(
    const float* __restrict__ hin, float* __restrict__ hout,
    float* __restrict__ nf, const float* __restrict__ x,
    const int* __restrict__ row_off, const int* __restrict__ poly_end,
    const int* __restrict__ pack,
    const float* __restrict__ W, const float* __restrict__ bias,
    const float* __restrict__ gamma, const float* __restrict__ beta,
    const float* __restrict__ gate, float* __restrict__ out)
{
    __shared__ float Wl[C_H * 129];          // W[c][k] at c*129+k: bank (c+k)%32 -> conflict-free reads
    __shared__ float aggL[4][NPW * C_H];     // per-wave agg rows

    for (int i = threadIdx.x; i < C_H * C_H; i += 256) {
        int c = i >> 7, k = i & 127;
        Wl[c * 129 + k] = W[i];              // coalesced read, conflict-free write
    }
    __syncthreads();

    const int l = threadIdx.x & 63, wid = threadIdx.x >> 6;
    const int wave = blockIdx.x * 4 + wid, nw = gridDim.x * 4;

    const float b0 = bias[l],  b1 = bias[l + 64];
    const float g0 = gamma[l], g1 = gamma[l + 64];
    const float e0 = beta[l],  e1 = beta[l + 64];
    float sg0 = 0.f, sg1 = 0.f;
    if (MODE <= 2) {
        sg0 = 1.f / (1.f + expf(-gate[l]));
        sg1 = 1.f / (1.f + expf(-gate[l + 64]));
    }

    float red0 = 0.f, red1 = 0.f;            // v2/v3 per-wave partial max (values >= 0)

    const float* __restrict__ hb = hin + 2 * l;

    for (int base = wave * NPW; base < N_NODES; base += nw * NPW) {
        bool anyp[NPW];
        // ---- aggregation (scatter-free segment max via CSR), 8-deep pipelined ----
        for (int j = 0; j < NPW; ++j) {
            const int n = base + j;
            float a0 = 0.f, a1 = 0.f;        // init 0 == "no incoming -> 0" (inputs >= 0)
            bool ap = false;
            if (n < N_NODES) {
                const int beg = row_off[n];
                const int end = (MODE == 3) ? poly_end[n] : row_off[n + 1];
                ap = (end > beg);
                int e = beg;
                for (; e + 8 <= end; e += 8) {
                    float2 v[8];
#pragma unroll
                    for (int t = 0; t < 8; ++t)
                        v[t] = *reinterpret_cast<const float2*>(hb + (size_t)pack[e + t] * C_H);
#pragma unroll
                    for (int t = 0; t < 8; ++t) {
                        a0 = fmaxf(a0, v[t].x);
                        a1 = fmaxf(a1, v[t].y);
                    }
                }
                for (; e + 2 <= end; e += 2) {
                    const float2 v0 = *reinterpret_cast<const float2*>(hb + (size_t)pack[e] * C_H);
                    const float2 v1 = *reinterpret_cast<const float2*>(hb + (size_t)pack[e + 1] * C_H);
                    a0 = fmaxf(a0, v0.x); a1 = fmaxf(a1, v0.y);
                    a0 = fmaxf(a0, v1.x); a1 = fmaxf(a1, v1.y);
                }
                if (e < end) {
                    const float2 v0 = *reinterpret_cast<const float2*>(hb + (size_t)pack[e] * C_H);
                    a0 = fmaxf(a0, v0.x); a1 = fmaxf(a1, v0.y);
                }
            }
            anyp[j] = ap;
            *reinterpret_cast<float2*>(&aggL[wid][j * C_H + 2 * l]) = make_float2(a0, a1);
        }
        // per-wave private LDS region: no __syncthreads needed (wave-internal dep)

        // ---- GEMM: out[c] = sum_k agg[k] * W[c][k] ----
        float acc[NPW][2];
#pragma unroll
        for (int j = 0; j < NPW; ++j) { acc[j][0] = 0.f; acc[j][1] = 0.f; }
#pragma unroll 4
        for (int k = 0; k < C_H; ++k) {
            const float w0 = Wl[l * 129 + k];
            const float w1 = Wl[(l + 64) * 129 + k];
#pragma unroll
            for (int j = 0; j < NPW; ++j) {
                const float a = aggL[wid][j * C_H + k];   // LDS broadcast
                acc[j][0] = fmaf(a, w0, acc[j][0]);
                acc[j][1] = fmaf(a, w1, acc[j][1]);
            }
        }

        // ---- epilogue: bias, LN, residual relu, nf/v-reductions ----
#pragma unroll
        for (int j = 0; j < NPW; ++j) {
            const int n = base + j;
            if (n < N_NODES) {               // wave-uniform branch
                float h0 = acc[j][0] + b0, h1 = acc[j][1] + b1;
                float s = h0 + h1, q = h0 * h0 + h1 * h1;
#pragma unroll
                for (int m = 1; m < 64; m <<= 1) {
                    s += __shfl_xor(s, m);
                    q += __shfl_xor(q, m);
                }
                const float mu  = s * (1.f / 128.f);
                const float var = q * (1.f / 128.f) - mu * mu;   // biased var
                const float rs  = rsqrtf(var + LN_EPS);
                const float r0 = hin[(size_t)n * C_H + l];
                const float r1 = hin[(size_t)n * C_H + l + 64];
                const float o0 = fmaxf((h0 - mu) * rs * g0 + e0 + r0, 0.f);
                const float o1 = fmaxf((h1 - mu) * rs * g1 + e1 + r1, 0.f);
                if (MODE <= 1) {
                    hout[(size_t)n * C_H + l]      = o0;
                    hout[(size_t)n * C_H + l + 64] = o1;
                }
                if (MODE == 0) {
                    nf[(size_t)n * C_H + l]      = o0 * sg0;
                    nf[(size_t)n * C_H + l + 64] = o1 * sg1;
                } else if (MODE == 1) {
                    nf[(size_t)n * C_H + l]      += o0 * sg0;
                    nf[(size_t)n * C_H + l + 64] += o1 * sg1;
                } else if (MODE == 2) {
                    const float f0 = nf[(size_t)n * C_H + l]      + o0 * sg0;
                    const float f1 = nf[(size_t)n * C_H + l + 64] + o1 * sg1;
                    nf[(size_t)n * C_H + l]      = f0;
                    nf[(size_t)n * C_H + l + 64] = f1;
                    if (x[(size_t)n * C_IN] <= 0.1f) {           // rem = !(x0 > 0.1)
                        red0 = fmaxf(red0, f0);
                        red1 = fmaxf(red1, f1);
                    }
                } else {                                          // MODE 3
                    if (anyp[j]) {                                // sink node (has poly in-edge)
                        red0 = fmaxf(red0, o0);
                        red1 = fmaxf(red1, o1);
                    }
                }
            }
        }
    }

    if (MODE >= 2) {
        __syncthreads();
        float* red = &aggL[0][0];
        red[wid * 128 + l]      = red0;
        red[wid * 128 + 64 + l] = red1;
        __syncthreads();
        if (threadIdx.x < 128) {
            const int c = threadIdx.x;
            const float m = fmaxf(fmaxf(red[c], red[128 + c]), fmaxf(red[256 + c], red[384 + c]));
            float* o = out + (MODE == 3 ? 0 : 128);
            atomicMax(reinterpret_cast<int*>(o + c), __float_as_int(m));  // m >= 0: int-max == float-max
        }
    }
}

// ---------------------------------------------------------------------------
extern "C" void kernel_launch(void* const* d_in, const int* in_sizes, int n_in,
                              void* d_out, int out_size, void* d_ws, size_t ws_size,
                              hipStream_t stream) {
    const float* x      = (const float*)d_in[0];
    const float* W_in   = (const float*)d_in[1];
    const float* b_in   = (const float*)d_in[2];
    const float* hop_W  = (const float*)d_in[3];
    const float* hop_b  = (const float*)d_in[4];
    const float* hop_g  = (const float*)d_in[5];
    const float* hop_be = (const float*)d_in[6];
    const float* gates  = (const float*)d_in[7];
    const float* fW     = (const float*)d_in[8];
    const float* fb     = (const float*)d_in[9];
    const float* fg     = (const float*)d_in[10];
    const float* fbe    = (const float*)d_in[11];
    const int*   eidx   = (const int*)d_in[12];
    const int*   eattr  = (const int*)d_in[13];
    float* out = (float*)d_out;

    char* ws = (char*)d_ws;
    size_t off = 0;
    auto alloc = [&](size_t bytes) {
        char* p = ws + off;
        off = (off + bytes + 255) & ~(size_t)255;
        return p;
    };
    int*   cnt      = (int*)alloc((size_t)N_NODES * 4);
    int*   pcnt     = (int*)alloc((size_t)N_NODES * 4);
    int*   curP     = (int*)alloc((size_t)N_NODES * 4);
    int*   curR     = (int*)alloc((size_t)N_NODES * 4);
    int*   row_off  = (int*)alloc((size_t)(N_NODES + 1) * 4);
    int*   polyend  = (int*)alloc((size_t)N_NODES * 4);
    int*   pack     = (int*)alloc((size_t)N_EDGES * 4);
    float* hA       = (float*)alloc((size_t)N_NODES * C_H * 4);
    float* hB       = (float*)alloc((size_t)N_NODES * C_H * 4);
    float* nf       = (float*)alloc((size_t)N_NODES * C_H * 4);
    (void)ws_size;

    const int* src = eidx;
    const int* dst = eidx + N_EDGES;

    hipMemsetAsync(cnt,  0, (size_t)N_NODES * 4, stream);
    hipMemsetAsync(pcnt, 0, (size_t)N_NODES * 4, stream);
    hipMemsetAsync(curP, 0, (size_t)N_NODES * 4, stream);
    hipMemsetAsync(curR, 0, (size_t)N_NODES * 4, stream);
    hipMemsetAsync(d_out, 0, 256 * 4, stream);   // v2/v3 accumulate via atomicMax (vals >= 0)

    hist_kernel<<<2048, 256, 0, stream>>>(dst, eattr, cnt, pcnt);
    scan_kernel<<<1, 1024, 0, stream>>>(cnt, pcnt, row_off, polyend);
    scatter_kernel<<<2048, 256, 0, stream>>>(src, dst, eattr, row_off, polyend, curP, curR, pack);
    in_proj_kernel<<<2048, 256, 0, stream>>>(x, W_in, b_in, hA);

    layer_kernel<0><<<512, 256, 0, stream>>>(hA, hB, nf, x, row_off, polyend, pack,
                                             hop_W + 0 * C_H * C_H, hop_b + 0 * C_H,
                                             hop_g + 0 * C_H, hop_be + 0 * C_H,
                                             gates + 0 * C_H, out);
    layer_kernel<1><<<512, 256, 0, stream>>>(hB, hA, nf, x, row_off, polyend, pack,
                                             hop_W + 1 * C_H * C_H, hop_b + 1 * C_H,
                                             hop_g + 1 * C_H, hop_be + 1 * C_H,
                                             gates + 1 * C_H, out);
    layer_kernel<2><<<512, 256, 0, stream>>>(hA, nullptr, nf, x, row_off, polyend, pack,
                                             hop_W + 2 * C_H * C_H, hop_b + 2 * C_H,
                                             hop_g + 2 * C_H, hop_be + 2 * C_H,
                                             gates + 2 * C_H, out);
    layer_kernel<3><<<512, 256, 0, stream>>>(nf, nullptr, nullptr, x, row_off, polyend, pack,
                                             fW, fb, fg, fbe, nullptr, out);
}

// Round 2
// 1011.736 us; speedup vs baseline: 2.2269x; 1.3267x over previous
//
#include <hip/hip_runtime.h>
#include <hip/hip_bf16.h>
#include <cstdint>

#define N_NODES 100000
#define N_EDGES 1600000
#define C_IN    10
#define C_H     128
#define LN_EPS  1e-5f

#define SCAN_BLOCKS 98   // ceil(N_NODES / 1024)

// ---------------------------------------------------------------------------
// CSR build: histogram of dst (total + poly), two-level exclusive scan,
// scatter with poly edges placed FIRST within each node's segment.
//   row_off[n] .. poly_end[n]   : poly (attr==3) edges
//   poly_end[n] .. row_off[n+1] : remaining edges
// ---------------------------------------------------------------------------
__global__ void hist_kernel(const int* __restrict__ dst, const int* __restrict__ attr,
                            int* __restrict__ cnt, int* __restrict__ pcnt) {
    int i = blockIdx.x * blockDim.x + threadIdx.x;
    int stride = gridDim.x * blockDim.x;
    for (; i < N_EDGES; i += stride) {
        int d = dst[i];
        atomicAdd(&cnt[d], 1);
        if (attr[i] == 3) atomicAdd(&pcnt[d], 1);
    }
}

__device__ inline int wave_incl_scan(int v, int lane) {
#pragma unroll
    for (int off = 1; off < 64; off <<= 1) {
        int n = __shfl_up(v, off);
        if (lane >= off) v += n;
    }
    return v;
}

// Per-block exclusive scan of cnt; block sums to bsum.
__global__ __launch_bounds__(1024) void scan1_kernel(const int* __restrict__ cnt,
                                                     int* __restrict__ excl,
                                                     int* __restrict__ bsum) {
    __shared__ int wsum[16];
    const int t = threadIdx.x, lane = t & 63, wid = t >> 6;
    const int i = blockIdx.x * 1024 + t;
    const int v = (i < N_NODES) ? cnt[i] : 0;
    int inc = wave_incl_scan(v, lane);
    if (lane == 63) wsum[wid] = inc;
    __syncthreads();
    if (t < 16) {
        int w = wsum[t];
#pragma unroll
        for (int off = 1; off < 16; off <<= 1) {
            int n = __shfl_up(w, off);
            if (t >= off) w += n;
        }
        wsum[t] = w;   // inclusive wave-sum prefix
    }
    __syncthreads();
    const int woff = (wid == 0) ? 0 : wsum[wid - 1];
    if (i < N_NODES) excl[i] = inc - v + woff;
    if (t == 0) bsum[blockIdx.x] = wsum[15];
}

// Exclusive scan of the SCAN_BLOCKS block sums (one tiny block).
__global__ void scan2_kernel(const int* __restrict__ bsum, int* __restrict__ bofs) {
    __shared__ int wsum[2];
    const int t = threadIdx.x, lane = t & 63, wid = t >> 6;
    const int v = (t < SCAN_BLOCKS) ? bsum[t] : 0;
    int inc = wave_incl_scan(v, lane);
    if (lane == 63) wsum[wid] = inc;
    __syncthreads();
    const int woff = (wid == 0) ? 0 : wsum[0];
    if (t < SCAN_BLOCKS) bofs[t] = inc - v + woff;
}

// Add block offsets; emit row_off and poly_end.
__global__ __launch_bounds__(1024) void scan3_kernel(const int* __restrict__ excl,
                                                     const int* __restrict__ bofs,
                                                     const int* __restrict__ pcnt,
                                                     int* __restrict__ row_off,
                                                     int* __restrict__ poly_end) {
    const int i = blockIdx.x * 1024 + threadIdx.x;
    if (i < N_NODES) {
        const int r = excl[i] + bofs[blockIdx.x];
        row_off[i]  = r;
        poly_end[i] = r + pcnt[i];
    }
    if (i == 0) row_off[N_NODES] = N_EDGES;
}

__global__ void scatter_kernel(const int* __restrict__ src, const int* __restrict__ dst,
                               const int* __restrict__ attr,
                               const int* __restrict__ row_off, const int* __restrict__ poly_end,
                               int* __restrict__ curP, int* __restrict__ curR,
                               int* __restrict__ pack) {
    int i = blockIdx.x * blockDim.x + threadIdx.x;
    int stride = gridDim.x * blockDim.x;
    for (; i < N_EDGES; i += stride) {
        int d = dst[i];
        int pos;
        if (attr[i] == 3) pos = row_off[d]  + atomicAdd(&curP[d], 1);
        else              pos = poly_end[d] + atomicAdd(&curR[d], 1);
        pack[pos] = src[i];  // order within a segment is nondeterministic; max is invariant
    }
}

// ---------------------------------------------------------------------------
// Input projection: h0 = relu(x @ W_in^T + b_in).  One wave per node,
// lane l owns channels (l, l+64). W_in in LDS with stride 11 (gcd(11,32)=1).
// ---------------------------------------------------------------------------
__global__ void in_proj_kernel(const float* __restrict__ x, const float* __restrict__ Win,
                               const float* __restrict__ bin, float* __restrict__ h0) {
    __shared__ float Wl[C_H * 11];
    for (int i = threadIdx.x; i < C_H * C_IN; i += blockDim.x) {
        int c = i / C_IN, k = i % C_IN;
        Wl[c * 11 + k] = Win[i];
    }
    __syncthreads();
    const int l = threadIdx.x & 63, wid = threadIdx.x >> 6;
    const int wave = blockIdx.x * 4 + wid, nw = gridDim.x * 4;
    const float b0 = bin[l], b1 = bin[l + 64];
    for (int n = wave; n < N_NODES; n += nw) {
        float xr[C_IN];
#pragma unroll
        for (int k = 0; k < C_IN; ++k) xr[k] = x[n * C_IN + k];  // wave-uniform
        float a0 = b0, a1 = b1;
#pragma unroll
        for (int k = 0; k < C_IN; ++k) {
            a0 = fmaf(xr[k], Wl[l * 11 + k], a0);
            a1 = fmaf(xr[k], Wl[(l + 64) * 11 + k], a1);
        }
        h0[(size_t)n * C_H + l]      = fmaxf(a0, 0.f);
        h0[(size_t)n * C_H + l + 64] = fmaxf(a1, 0.f);
    }
}

// ---------------------------------------------------------------------------
// Fused MPNN layer: gather-max -> GEMM -> LN -> residual ReLU -> epilogue
// MODE 0: hop0  (hout, nf  = o*sg)
// MODE 1: hop1  (hout, nf += o*sg)
// MODE 2: hop2  (no hout, nf += o*sg, v3 = max over rem nodes of nf)
// MODE 3: final (no hout/nf, poly-only agg via poly_end, v2 = max over sinks)
// One wave per node, 4 nodes per wave-iteration (NPW=4).
// Lane l: gathers channels (2l,2l+1); computes output channels (l,l+64).
// Gather is software-pipelined 8 edges deep (MLP 1 -> 8).
// ---------------------------------------------------------------------------
#define NPW 4

template <int MODE>
__global__ __launch_bounds__(256) void layer_kernel(
    const float* __restrict__ hin, float* __restrict__ hout,
    float* __restrict__ nf, const float* __restrict__ x,
    const int* __restrict__ row_off, const int* __restrict__ poly_end,
    const int* __restrict__ pack,
    const float* __restrict__ W, const float* __restrict__ bias,
    const float* __restrict__ gamma, const float* __restrict__ beta,
    const float* __restrict__ gate, float* __restrict__ out)
{
    __shared__ float Wl[C_H * 129];          // W[c][k] at c*129+k: bank (c+k)%32 -> conflict-free reads
    __shared__ float aggL[4][NPW * C_H];     // per-wave agg rows

    for (int i = threadIdx.x; i < C_H * C_H; i += 256) {
        int c = i >> 7, k = i & 127;
        Wl[c * 129 + k] = W[i];              // coalesced read, conflict-free write
    }
    __syncthreads();

    const int l = threadIdx.x & 63, wid = threadIdx.x >> 6;
    const int wave = blockIdx.x * 4 + wid, nw = gridDim.x * 4;

    const float b0 = bias[l],  b1 = bias[l + 64];
    const float g0 = gamma[l], g1 = gamma[l + 64];
    const float e0 = beta[l],  e1 = beta[l + 64];
    float sg0 = 0.f, sg1 = 0.f;
    if (MODE <= 2) {
        sg0 = 1.f / (1.f + expf(-gate[l]));
        sg1 = 1.f / (1.f + expf(-gate[l + 64]));
    }

    float red0 = 0.f, red1 = 0.f;            // v2/v3 per-wave partial max (values >= 0)

    const float* __restrict__ hb = hin + 2 * l;

    for (int base = wave * NPW; base < N_NODES; base += nw * NPW) {
        bool anyp[NPW];
        // ---- aggregation (scatter-free segment max via CSR), 8-deep pipelined ----
        for (int j = 0; j < NPW; ++j) {
            const int n = base + j;
            float a0 = 0.f, a1 = 0.f;        // init 0 == "no incoming -> 0" (inputs >= 0)
            bool ap = false;
            if (n < N_NODES) {
                const int beg = row_off[n];
                const int end = (MODE == 3) ? poly_end[n] : row_off[n + 1];
                ap = (end > beg);
                int e = beg;
                for (; e + 8 <= end; e += 8) {
                    float2 v[8];
#pragma unroll
                    for (int t = 0; t < 8; ++t)
                        v[t] = *reinterpret_cast<const float2*>(hb + (size_t)pack[e + t] * C_H);
#pragma unroll
                    for (int t = 0; t < 8; ++t) {
                        a0 = fmaxf(a0, v[t].x);
                        a1 = fmaxf(a1, v[t].y);
                    }
                }
                for (; e + 2 <= end; e += 2) {
                    const float2 v0 = *reinterpret_cast<const float2*>(hb + (size_t)pack[e] * C_H);
                    const float2 v1 = *reinterpret_cast<const float2*>(hb + (size_t)pack[e + 1] * C_H);
                    a0 = fmaxf(a0, v0.x); a1 = fmaxf(a1, v0.y);
                    a0 = fmaxf(a0, v1.x); a1 = fmaxf(a1, v1.y);
                }
                if (e < end) {
                    const float2 v0 = *reinterpret_cast<const float2*>(hb + (size_t)pack[e] * C_H);
                    a0 = fmaxf(a0, v0.x); a1 = fmaxf(a1, v0.y);
                }
            }
            anyp[j] = ap;
            *reinterpret_cast<float2*>(&aggL[wid][j * C_H + 2 * l]) = make_float2(a0, a1);
        }
        // per-wave private LDS region: no __syncthreads needed (wave-internal dep)

        // ---- GEMM: out[c] = sum_k agg[k] * W[c][k] ----
        float acc[NPW][2];
#pragma unroll
        for (int j = 0; j < NPW; ++j) { acc[j][0] = 0.f; acc[j][1] = 0.f; }
#pragma unroll 4
        for (int k = 0; k < C_H; ++k) {
            const float w0 = Wl[l * 129 + k];
            const float w1 = Wl[(l + 64) * 129 + k];
#pragma unroll
            for (int j = 0; j < NPW; ++j) {
                const float a = aggL[wid][j * C_H + k];   // LDS broadcast
                acc[j][0] = fmaf(a, w0, acc[j][0]);
                acc[j][1] = fmaf(a, w1, acc[j][1]);
            }
        }

        // ---- epilogue: bias, LN, residual relu, nf/v-reductions ----
#pragma unroll
        for (int j = 0; j < NPW; ++j) {
            const int n = base + j;
            if (n < N_NODES) {               // wave-uniform branch
                float h0 = acc[j][0] + b0, h1 = acc[j][1] + b1;
                float s = h0 + h1, q = h0 * h0 + h1 * h1;
#pragma unroll
                for (int m = 1; m < 64; m <<= 1) {
                    s += __shfl_xor(s, m);
                    q += __shfl_xor(q, m);
                }
                const float mu  = s * (1.f / 128.f);
                const float var = q * (1.f / 128.f) - mu * mu;   // biased var
                const float rs  = rsqrtf(var + LN_EPS);
                const float r0 = hin[(size_t)n * C_H + l];
                const float r1 = hin[(size_t)n * C_H + l + 64];
                const float o0 = fmaxf((h0 - mu) * rs * g0 + e0 + r0, 0.f);
                const float o1 = fmaxf((h1 - mu) * rs * g1 + e1 + r1, 0.f);
                if (MODE <= 1) {
                    hout[(size_t)n * C_H + l]      = o0;
                    hout[(size_t)n * C_H + l + 64] = o1;
                }
                if (MODE == 0) {
                    nf[(size_t)n * C_H + l]      = o0 * sg0;
                    nf[(size_t)n * C_H + l + 64] = o1 * sg1;
                } else if (MODE == 1) {
                    nf[(size_t)n * C_H + l]      += o0 * sg0;
                    nf[(size_t)n * C_H + l + 64] += o1 * sg1;
                } else if (MODE == 2) {
                    const float f0 = nf[(size_t)n * C_H + l]      + o0 * sg0;
                    const float f1 = nf[(size_t)n * C_H + l + 64] + o1 * sg1;
                    nf[(size_t)n * C_H + l]      = f0;
                    nf[(size_t)n * C_H + l + 64] = f1;
                    if (x[(size_t)n * C_IN] <= 0.1f) {           // rem = !(x0 > 0.1)
                        red0 = fmaxf(red0, f0);
                        red1 = fmaxf(red1, f1);
                    }
                } else {                                          // MODE 3
                    if (anyp[j]) {                                // sink node (has poly in-edge)
                        red0 = fmaxf(red0, o0);
                        red1 = fmaxf(red1, o1);
                    }
                }
            }
        }
    }

    if (MODE >= 2) {
        __syncthreads();
        float* red = &aggL[0][0];
        red[wid * 128 + l]      = red0;
        red[wid * 128 + 64 + l] = red1;
        __syncthreads();
        if (threadIdx.x < 128) {
            const int c = threadIdx.x;
            const float m = fmaxf(fmaxf(red[c], red[128 + c]), fmaxf(red[256 + c], red[384 + c]));
            float* o = out + (MODE == 3 ? 0 : 128);
            atomicMax(reinterpret_cast<int*>(o + c), __float_as_int(m));  // m >= 0: int-max == float-max
        }
    }
}

// ---------------------------------------------------------------------------
extern "C" void kernel_launch(void* const* d_in, const int* in_sizes, int n_in,
                              void* d_out, int out_size, void* d_ws, size_t ws_size,
                              hipStream_t stream) {
    const float* x      = (const float*)d_in[0];
    const float* W_in   = (const float*)d_in[1];
    const float* b_in   = (const float*)d_in[2];
    const float* hop_W  = (const float*)d_in[3];
    const float* hop_b  = (const float*)d_in[4];
    const float* hop_g  = (const float*)d_in[5];
    const float* hop_be = (const float*)d_in[6];
    const float* gates  = (const float*)d_in[7];
    const float* fW     = (const float*)d_in[8];
    const float* fb     = (const float*)d_in[9];
    const float* fg     = (const float*)d_in[10];
    const float* fbe    = (const float*)d_in[11];
    const int*   eidx   = (const int*)d_in[12];
    const int*   eattr  = (const int*)d_in[13];
    float* out = (float*)d_out;

    char* ws = (char*)d_ws;
    size_t off = 0;
    auto alloc = [&](size_t bytes) {
        char* p = ws + off;
        off = (off + bytes + 255) & ~(size_t)255;
        return p;
    };
    int*   cnt      = (int*)alloc((size_t)N_NODES * 4);
    int*   pcnt     = (int*)alloc((size_t)N_NODES * 4);
    int*   curP     = (int*)alloc((size_t)N_NODES * 4);
    int*   curR     = (int*)alloc((size_t)N_NODES * 4);
    int*   excl     = (int*)alloc((size_t)N_NODES * 4);
    int*   bsum     = (int*)alloc((size_t)SCAN_BLOCKS * 4);
    int*   bofs     = (int*)alloc((size_t)SCAN_BLOCKS * 4);
    int*   row_off  = (int*)alloc((size_t)(N_NODES + 1) * 4);
    int*   polyend  = (int*)alloc((size_t)N_NODES * 4);
    int*   pack     = (int*)alloc((size_t)N_EDGES * 4);
    float* hA       = (float*)alloc((size_t)N_NODES * C_H * 4);
    float* hB       = (float*)alloc((size_t)N_NODES * C_H * 4);
    float* nf       = (float*)alloc((size_t)N_NODES * C_H * 4);
    (void)ws_size;

    const int* src = eidx;
    const int* dst = eidx + N_EDGES;

    hipMemsetAsync(cnt,  0, (size_t)N_NODES * 4, stream);
    hipMemsetAsync(pcnt, 0, (size_t)N_NODES * 4, stream);
    hipMemsetAsync(curP, 0, (size_t)N_NODES * 4, stream);
    hipMemsetAsync(curR, 0, (size_t)N_NODES * 4, stream);
    hipMemsetAsync(d_out, 0, 256 * 4, stream);   // v2/v3 accumulate via atomicMax (vals >= 0)

    hist_kernel<<<2048, 256, 0, stream>>>(dst, eattr, cnt, pcnt);
    scan1_kernel<<<SCAN_BLOCKS, 1024, 0, stream>>>(cnt, excl, bsum);
    scan2_kernel<<<1, 128, 0, stream>>>(bsum, bofs);
    scan3_kernel<<<SCAN_BLOCKS, 1024, 0, stream>>>(excl, bofs, pcnt, row_off, polyend);
    scatter_kernel<<<2048, 256, 0, stream>>>(src, dst, eattr, row_off, polyend, curP, curR, pack);
    in_proj_kernel<<<2048, 256, 0, stream>>>(x, W_in, b_in, hA);

    layer_kernel<0><<<512, 256, 0, stream>>>(hA, hB, nf, x, row_off, polyend, pack,
                                             hop_W + 0 * C_H * C_H, hop_b + 0 * C_H,
                                             hop_g + 0 * C_H, hop_be + 0 * C_H,
                                             gates + 0 * C_H, out);
    layer_kernel<1><<<512, 256, 0, stream>>>(hB, hA, nf, x, row_off, polyend, pack,
                                             hop_W + 1 * C_H * C_H, hop_b + 1 * C_H,
                                             hop_g + 1 * C_H, hop_be + 1 * C_H,
                                             gates + 1 * C_H, out);
    layer_kernel<2><<<512, 256, 0, stream>>>(hA, nullptr, nf, x, row_off, polyend, pack,
                                             hop_W + 2 * C_H * C_H, hop_b + 2 * C_H,
                                             hop_g + 2 * C_H, hop_be + 2 * C_H,
                                             gates + 2 * C_H, out);
    layer_kernel<3><<<512, 256, 0, stream>>>(nf, nullptr, nullptr, x, row_off, polyend, pack,
                                             fW, fb, fg, fbe, nullptr, out);
}

// Round 3
// 812.262 us; speedup vs baseline: 2.7738x; 1.2456x over previous
//
#include <hip/hip_runtime.h>
#include <hip/hip_bf16.h>
#include <cstdint>

#define N_NODES 100000
#define N_EDGES 1600000
#define C_IN    10
#define C_H     128
#define LN_EPS  1e-5f

#define SCAN_BLOCKS 98   // ceil(N_NODES / 1024)

// ---------------------------------------------------------------------------
// CSR build: histogram of dst (total + poly), two-level exclusive scan,
// scatter with poly edges placed FIRST within each node's segment.
//   row_off[n] .. poly_end[n]   : poly (attr==3) edges
//   poly_end[n] .. row_off[n+1] : remaining edges
// ---------------------------------------------------------------------------
__global__ void hist_kernel(const int* __restrict__ dst, const int* __restrict__ attr,
                            int* __restrict__ cnt, int* __restrict__ pcnt) {
    int i = blockIdx.x * blockDim.x + threadIdx.x;
    int stride = gridDim.x * blockDim.x;
    for (; i < N_EDGES; i += stride) {
        int d = dst[i];
        atomicAdd(&cnt[d], 1);
        if (attr[i] == 3) atomicAdd(&pcnt[d], 1);
    }
}

__device__ inline int wave_incl_scan(int v, int lane) {
#pragma unroll
    for (int off = 1; off < 64; off <<= 1) {
        int n = __shfl_up(v, off);
        if (lane >= off) v += n;
    }
    return v;
}

// Per-block exclusive scan of cnt; block sums to bsum.
__global__ __launch_bounds__(1024) void scan1_kernel(const int* __restrict__ cnt,
                                                     int* __restrict__ excl,
                                                     int* __restrict__ bsum) {
    __shared__ int wsum[16];
    const int t = threadIdx.x, lane = t & 63, wid = t >> 6;
    const int i = blockIdx.x * 1024 + t;
    const int v = (i < N_NODES) ? cnt[i] : 0;
    int inc = wave_incl_scan(v, lane);
    if (lane == 63) wsum[wid] = inc;
    __syncthreads();
    if (t < 16) {
        int w = wsum[t];
#pragma unroll
        for (int off = 1; off < 16; off <<= 1) {
            int n = __shfl_up(w, off);
            if (t >= off) w += n;
        }
        wsum[t] = w;   // inclusive wave-sum prefix
    }
    __syncthreads();
    const int woff = (wid == 0) ? 0 : wsum[wid - 1];
    if (i < N_NODES) excl[i] = inc - v + woff;
    if (t == 0) bsum[blockIdx.x] = wsum[15];
}

// Exclusive scan of the SCAN_BLOCKS block sums (one tiny block).
__global__ void scan2_kernel(const int* __restrict__ bsum, int* __restrict__ bofs) {
    __shared__ int wsum[2];
    const int t = threadIdx.x, lane = t & 63, wid = t >> 6;
    const int v = (t < SCAN_BLOCKS) ? bsum[t] : 0;
    int inc = wave_incl_scan(v, lane);
    if (lane == 63) wsum[wid] = inc;
    __syncthreads();
    const int woff = (wid == 0) ? 0 : wsum[0];
    if (t < SCAN_BLOCKS) bofs[t] = inc - v + woff;
}

// Add block offsets; emit row_off and poly_end.
__global__ __launch_bounds__(1024) void scan3_kernel(const int* __restrict__ excl,
                                                     const int* __restrict__ bofs,
                                                     const int* __restrict__ pcnt,
                                                     int* __restrict__ row_off,
                                                     int* __restrict__ poly_end) {
    const int i = blockIdx.x * 1024 + threadIdx.x;
    if (i < N_NODES) {
        const int r = excl[i] + bofs[blockIdx.x];
        row_off[i]  = r;
        poly_end[i] = r + pcnt[i];
    }
    if (i == 0) row_off[N_NODES] = N_EDGES;
}

__global__ void scatter_kernel(const int* __restrict__ src, const int* __restrict__ dst,
                               const int* __restrict__ attr,
                               const int* __restrict__ row_off, const int* __restrict__ poly_end,
                               int* __restrict__ curP, int* __restrict__ curR,
                               int* __restrict__ pack) {
    int i = blockIdx.x * blockDim.x + threadIdx.x;
    int stride = gridDim.x * blockDim.x;
    for (; i < N_EDGES; i += stride) {
        int d = dst[i];
        int pos;
        if (attr[i] == 3) pos = row_off[d]  + atomicAdd(&curP[d], 1);
        else              pos = poly_end[d] + atomicAdd(&curR[d], 1);
        pack[pos] = src[i];  // order within a segment is nondeterministic; max is invariant
    }
}

// ---------------------------------------------------------------------------
// Input projection: h0 = relu(x @ W_in^T + b_in).  One wave per node,
// lane l owns channels (l, l+64). W_in in LDS with stride 11 (gcd(11,32)=1).
// ---------------------------------------------------------------------------
__global__ void in_proj_kernel(const float* __restrict__ x, const float* __restrict__ Win,
                               const float* __restrict__ bin, float* __restrict__ h0) {
    __shared__ float Wl[C_H * 11];
    for (int i = threadIdx.x; i < C_H * C_IN; i += blockDim.x) {
        int c = i / C_IN, k = i % C_IN;
        Wl[c * 11 + k] = Win[i];
    }
    __syncthreads();
    const int l = threadIdx.x & 63, wid = threadIdx.x >> 6;
    const int wave = blockIdx.x * 4 + wid, nw = gridDim.x * 4;
    const float b0 = bin[l], b1 = bin[l + 64];
    for (int n = wave; n < N_NODES; n += nw) {
        float xr[C_IN];
#pragma unroll
        for (int k = 0; k < C_IN; ++k) xr[k] = x[n * C_IN + k];  // wave-uniform
        float a0 = b0, a1 = b1;
#pragma unroll
        for (int k = 0; k < C_IN; ++k) {
            a0 = fmaf(xr[k], Wl[l * 11 + k], a0);
            a1 = fmaf(xr[k], Wl[(l + 64) * 11 + k], a1);
        }
        h0[(size_t)n * C_H + l]      = fmaxf(a0, 0.f);
        h0[(size_t)n * C_H + l + 64] = fmaxf(a1, 0.f);
    }
}

// ---------------------------------------------------------------------------
// Fused MPNN layer: gather-max -> GEMM -> LN -> residual ReLU -> epilogue
// MODE 0: hop0  (hout, nf  = o*sg)
// MODE 1: hop1  (hout, nf += o*sg)
// MODE 2: hop2  (no hout, nf += o*sg, v3 = max over rem nodes of nf)
// MODE 3: final (no hout/nf, poly-only agg via poly_end, v2 = max over sinks)
// 1024-thread block = 16 waves sharing ONE LDS copy of W (66 KB): LDS total
// 98 KB -> 1 block/CU but 16 waves/CU (2x the old 8).  Gather MLP doubles.
// Lane l: gathers channels (2l,2l+1); computes output channels (l,l+64).
// Gather is software-pipelined 8 edges deep (8 loads in flight per wave).
// ---------------------------------------------------------------------------
#define NPW 4
#define LWAVES 16

template <int MODE>
__global__ __launch_bounds__(1024) void layer_kernel(
    const float* __restrict__ hin, float* __restrict__ hout,
    float* __restrict__ nf, const float* __restrict__ x,
    const int* __restrict__ row_off, const int* __restrict__ poly_end,
    const int* __restrict__ pack,
    const float* __restrict__ W, const float* __restrict__ bias,
    const float* __restrict__ gamma, const float* __restrict__ beta,
    const float* __restrict__ gate, float* __restrict__ out)
{
    __shared__ float Wl[C_H * 129];              // W[c][k] at c*129+k: bank (c+k)%32 -> conflict-free
    __shared__ float aggL[LWAVES][NPW * C_H];    // per-wave agg rows (wave-private)

    for (int i = threadIdx.x; i < C_H * C_H; i += 1024) {
        int c = i >> 7, k = i & 127;
        Wl[c * 129 + k] = W[i];                  // coalesced read, conflict-free write
    }
    __syncthreads();

    const int l = threadIdx.x & 63, wid = threadIdx.x >> 6;
    const int wave = blockIdx.x * LWAVES + wid, nw = gridDim.x * LWAVES;

    const float b0 = bias[l],  b1 = bias[l + 64];
    const float g0 = gamma[l], g1 = gamma[l + 64];
    const float e0 = beta[l],  e1 = beta[l + 64];
    float sg0 = 0.f, sg1 = 0.f;
    if (MODE <= 2) {
        sg0 = 1.f / (1.f + expf(-gate[l]));
        sg1 = 1.f / (1.f + expf(-gate[l + 64]));
    }

    float red0 = 0.f, red1 = 0.f;                // v2/v3 per-wave partial max (values >= 0)

    const float* __restrict__ hb = hin + 2 * l;

    for (int base = wave * NPW; base < N_NODES; base += nw * NPW) {
        bool anyp[NPW];
        // ---- aggregation (scatter-free segment max via CSR), 8-deep pipelined ----
        for (int j = 0; j < NPW; ++j) {
            const int n = base + j;
            float a0 = 0.f, a1 = 0.f;            // init 0 == "no incoming -> 0" (inputs >= 0)
            bool ap = false;
            if (n < N_NODES) {
                const int beg = row_off[n];
                const int end = (MODE == 3) ? poly_end[n] : row_off[n + 1];
                ap = (end > beg);
                int e = beg;
                for (; e + 8 <= end; e += 8) {
                    float2 v[8];
#pragma unroll
                    for (int t = 0; t < 8; ++t)
                        v[t] = *reinterpret_cast<const float2*>(hb + (size_t)pack[e + t] * C_H);
#pragma unroll
                    for (int t = 0; t < 8; ++t) {
                        a0 = fmaxf(a0, v[t].x);
                        a1 = fmaxf(a1, v[t].y);
                    }
                }
                for (; e + 2 <= end; e += 2) {
                    const float2 v0 = *reinterpret_cast<const float2*>(hb + (size_t)pack[e] * C_H);
                    const float2 v1 = *reinterpret_cast<const float2*>(hb + (size_t)pack[e + 1] * C_H);
                    a0 = fmaxf(a0, v0.x); a1 = fmaxf(a1, v0.y);
                    a0 = fmaxf(a0, v1.x); a1 = fmaxf(a1, v1.y);
                }
                if (e < end) {
                    const float2 v0 = *reinterpret_cast<const float2*>(hb + (size_t)pack[e] * C_H);
                    a0 = fmaxf(a0, v0.x); a1 = fmaxf(a1, v0.y);
                }
            }
            anyp[j] = ap;
            *reinterpret_cast<float2*>(&aggL[wid][j * C_H + 2 * l]) = make_float2(a0, a1);
        }
        // per-wave private LDS region: no __syncthreads needed (wave-internal dep)

        // ---- GEMM: out[c] = sum_k agg[k] * W[c][k] ----
        float acc[NPW][2];
#pragma unroll
        for (int j = 0; j < NPW; ++j) { acc[j][0] = 0.f; acc[j][1] = 0.f; }
#pragma unroll 4
        for (int k = 0; k < C_H; ++k) {
            const float w0 = Wl[l * 129 + k];
            const float w1 = Wl[(l + 64) * 129 + k];
#pragma unroll
            for (int j = 0; j < NPW; ++j) {
                const float a = aggL[wid][j * C_H + k];   // LDS broadcast
                acc[j][0] = fmaf(a, w0, acc[j][0]);
                acc[j][1] = fmaf(a, w1, acc[j][1]);
            }
        }

        // ---- epilogue: bias, LN, residual relu, nf/v-reductions ----
#pragma unroll
        for (int j = 0; j < NPW; ++j) {
            const int n = base + j;
            if (n < N_NODES) {               // wave-uniform branch
                float h0 = acc[j][0] + b0, h1 = acc[j][1] + b1;
                float s = h0 + h1, q = h0 * h0 + h1 * h1;
#pragma unroll
                for (int m = 1; m < 64; m <<= 1) {
                    s += __shfl_xor(s, m);
                    q += __shfl_xor(q, m);
                }
                const float mu  = s * (1.f / 128.f);
                const float var = q * (1.f / 128.f) - mu * mu;   // biased var
                const float rs  = rsqrtf(var + LN_EPS);
                const float r0 = hin[(size_t)n * C_H + l];
                const float r1 = hin[(size_t)n * C_H + l + 64];
                const float o0 = fmaxf((h0 - mu) * rs * g0 + e0 + r0, 0.f);
                const float o1 = fmaxf((h1 - mu) * rs * g1 + e1 + r1, 0.f);
                if (MODE <= 1) {
                    hout[(size_t)n * C_H + l]      = o0;
                    hout[(size_t)n * C_H + l + 64] = o1;
                }
                if (MODE == 0) {
                    nf[(size_t)n * C_H + l]      = o0 * sg0;
                    nf[(size_t)n * C_H + l + 64] = o1 * sg1;
                } else if (MODE == 1) {
                    nf[(size_t)n * C_H + l]      += o0 * sg0;
                    nf[(size_t)n * C_H + l + 64] += o1 * sg1;
                } else if (MODE == 2) {
                    const float f0 = nf[(size_t)n * C_H + l]      + o0 * sg0;
                    const float f1 = nf[(size_t)n * C_H + l + 64] + o1 * sg1;
                    nf[(size_t)n * C_H + l]      = f0;
                    nf[(size_t)n * C_H + l + 64] = f1;
                    if (x[(size_t)n * C_IN] <= 0.1f) {           // rem = !(x0 > 0.1)
                        red0 = fmaxf(red0, f0);
                        red1 = fmaxf(red1, f1);
                    }
                } else {                                          // MODE 3
                    if (anyp[j]) {                                // sink node (has poly in-edge)
                        red0 = fmaxf(red0, o0);
                        red1 = fmaxf(red1, o1);
                    }
                }
            }
        }
    }

    if (MODE >= 2) {
        __syncthreads();
        float* red = &aggL[0][0];
        red[wid * 128 + l]      = red0;
        red[wid * 128 + 64 + l] = red1;
        __syncthreads();
        if (threadIdx.x < 128) {
            const int c = threadIdx.x;
            float m = red[c];
#pragma unroll
            for (int w = 1; w < LWAVES; ++w) m = fmaxf(m, red[w * 128 + c]);
            float* o = out + (MODE == 3 ? 0 : 128);
            atomicMax(reinterpret_cast<int*>(o + c), __float_as_int(m));  // m >= 0: int-max == float-max
        }
    }
}

// ---------------------------------------------------------------------------
extern "C" void kernel_launch(void* const* d_in, const int* in_sizes, int n_in,
                              void* d_out, int out_size, void* d_ws, size_t ws_size,
                              hipStream_t stream) {
    const float* x      = (const float*)d_in[0];
    const float* W_in   = (const float*)d_in[1];
    const float* b_in   = (const float*)d_in[2];
    const float* hop_W  = (const float*)d_in[3];
    const float* hop_b  = (const float*)d_in[4];
    const float* hop_g  = (const float*)d_in[5];
    const float* hop_be = (const float*)d_in[6];
    const float* gates  = (const float*)d_in[7];
    const float* fW     = (const float*)d_in[8];
    const float* fb     = (const float*)d_in[9];
    const float* fg     = (const float*)d_in[10];
    const float* fbe    = (const float*)d_in[11];
    const int*   eidx   = (const int*)d_in[12];
    const int*   eattr  = (const int*)d_in[13];
    float* out = (float*)d_out;

    char* ws = (char*)d_ws;
    size_t off = 0;
    auto alloc = [&](size_t bytes) {
        char* p = ws + off;
        off = (off + bytes + 255) & ~(size_t)255;
        return p;
    };
    int*   cnt      = (int*)alloc((size_t)N_NODES * 4);
    int*   pcnt     = (int*)alloc((size_t)N_NODES * 4);
    int*   curP     = (int*)alloc((size_t)N_NODES * 4);
    int*   curR     = (int*)alloc((size_t)N_NODES * 4);
    int*   excl     = (int*)alloc((size_t)N_NODES * 4);
    int*   bsum     = (int*)alloc((size_t)SCAN_BLOCKS * 4);
    int*   bofs     = (int*)alloc((size_t)SCAN_BLOCKS * 4);
    int*   row_off  = (int*)alloc((size_t)(N_NODES + 1) * 4);
    int*   polyend  = (int*)alloc((size_t)N_NODES * 4);
    int*   pack     = (int*)alloc((size_t)N_EDGES * 4);
    float* hA       = (float*)alloc((size_t)N_NODES * C_H * 4);
    float* hB       = (float*)alloc((size_t)N_NODES * C_H * 4);
    float* nf       = (float*)alloc((size_t)N_NODES * C_H * 4);
    (void)ws_size;

    const int* src = eidx;
    const int* dst = eidx + N_EDGES;

    hipMemsetAsync(cnt,  0, (size_t)N_NODES * 4, stream);
    hipMemsetAsync(pcnt, 0, (size_t)N_NODES * 4, stream);
    hipMemsetAsync(curP, 0, (size_t)N_NODES * 4, stream);
    hipMemsetAsync(curR, 0, (size_t)N_NODES * 4, stream);
    hipMemsetAsync(d_out, 0, 256 * 4, stream);   // v2/v3 accumulate via atomicMax (vals >= 0)

    hist_kernel<<<2048, 256, 0, stream>>>(dst, eattr, cnt, pcnt);
    scan1_kernel<<<SCAN_BLOCKS, 1024, 0, stream>>>(cnt, excl, bsum);
    scan2_kernel<<<1, 128, 0, stream>>>(bsum, bofs);
    scan3_kernel<<<SCAN_BLOCKS, 1024, 0, stream>>>(excl, bofs, pcnt, row_off, polyend);
    scatter_kernel<<<2048, 256, 0, stream>>>(src, dst, eattr, row_off, polyend, curP, curR, pack);
    in_proj_kernel<<<2048, 256, 0, stream>>>(x, W_in, b_in, hA);

    layer_kernel<0><<<256, 1024, 0, stream>>>(hA, hB, nf, x, row_off, polyend, pack,
                                              hop_W + 0 * C_H * C_H, hop_b + 0 * C_H,
                                              hop_g + 0 * C_H, hop_be + 0 * C_H,
                                              gates + 0 * C_H, out);
    layer_kernel<1><<<256, 1024, 0, stream>>>(hB, hA, nf, x, row_off, polyend, pack,
                                              hop_W + 1 * C_H * C_H, hop_b + 1 * C_H,
                                              hop_g + 1 * C_H, hop_be + 1 * C_H,
                                              gates + 1 * C_H, out);
    layer_kernel<2><<<256, 1024, 0, stream>>>(hA, nullptr, nf, x, row_off, polyend, pack,
                                              hop_W + 2 * C_H * C_H, hop_b + 2 * C_H,
                                              hop_g + 2 * C_H, hop_be + 2 * C_H,
                                              gates + 2 * C_H, out);
    layer_kernel<3><<<256, 1024, 0, stream>>>(nf, nullptr, nullptr, x, row_off, polyend, pack,
                                              fW, fb, fg, fbe, nullptr, out);
}